// Round 1
// baseline (202.520 us; speedup 1.0000x reference)
//
#include <hip/hip_runtime.h>
#include <math.h>

#define HDIM 512
#define WDIM 512
#define PADW 512   // pad each side of the LDS row so j +/- r never goes OOB

// ---------------- zero the fp64 accumulator ----------------
__global__ void zero_acc_kernel(double* acc) { *acc = 0.0; }

// ---------------- pass 1: vertical 1D distances, squared ----------------
// One thread per (b, w) column. Forward scan stores running d; backward scan
// combines: g = min(min(d_fwd, d_bwd), 1e6); writes f = g*g in place.
// f1: mask = (1 - tgt)  (foreground where tgt != 1, features at tgt == 1)
// f0: mask = tgt        (foreground where tgt != 0, features at tgt == 0)
__global__ void vert_pass_kernel(const int* __restrict__ tgt,
                                 float* __restrict__ f1,
                                 float* __restrict__ f0,
                                 int B) {
    int t = blockIdx.x * blockDim.x + threadIdx.x;
    int total = B * WDIM;
    if (t >= total) return;
    int b = t / WDIM;
    int w = t - b * WDIM;
    size_t base = (size_t)b * HDIM * WDIM + w;
    const int* col = tgt + base;
    float* c1 = f1 + base;
    float* c0 = f0 + base;

    float d1 = 1.0e6f, d0 = 1.0e6f;
    // forward scan (matches jax.lax.scan: carry updated, then emitted)
    for (int h = 0; h < HDIM; ++h) {
        int tv = col[(size_t)h * WDIM];
        d1 = (tv != 1) ? d1 + 1.0f : 0.0f;
        d0 = (tv != 0) ? d0 + 1.0f : 0.0f;
        c1[(size_t)h * WDIM] = d1;
        c0[(size_t)h * WDIM] = d0;
    }
    // backward scan + combine
    d1 = 1.0e6f; d0 = 1.0e6f;
    for (int h = HDIM - 1; h >= 0; --h) {
        int tv = col[(size_t)h * WDIM];
        d1 = (tv != 1) ? d1 + 1.0f : 0.0f;
        d0 = (tv != 0) ? d0 + 1.0f : 0.0f;
        float g1 = fminf(fminf(c1[(size_t)h * WDIM], d1), 1.0e6f);
        float g0 = fminf(fminf(c0[(size_t)h * WDIM], d0), 1.0e6f);
        c1[(size_t)h * WDIM] = g1 * g1;
        c0[(size_t)h * WDIM] = g0 * g0;
    }
}

// ---------------- pass 2: horizontal parabola min + fused reduction ----------------
// One block per row (b,h). D[j] = min_k (j-k)^2 + f[k]; expand r outward from j,
// early-exit when r^2 >= best (exact: f >= 0, fp32 add of non-negatives is
// monotone). Then dist = sqrt(D1) - sqrt(D0); accumulate sigmoid(x)*dist.
__global__ __launch_bounds__(256) void horiz_pass_kernel(const float* __restrict__ f1,
                                                         const float* __restrict__ f0,
                                                         const float* __restrict__ outp,
                                                         double* __restrict__ acc) {
    __shared__ float s1[WDIM + 2 * PADW];
    __shared__ float s0[WDIM + 2 * PADW];
    __shared__ double swave[4];

    int rid = blockIdx.x;            // row index in [0, B*H)
    size_t base = (size_t)rid * WDIM;
    int tid = threadIdx.x;

    // fill with huge sentinel (never wins: real candidates <= 1e12 + 511^2)
    for (int i = tid; i < WDIM + 2 * PADW; i += 256) {
        s1[i] = 3.0e12f;
        s0[i] = 3.0e12f;
    }
    __syncthreads();
    for (int j = tid; j < WDIM; j += 256) {
        s1[PADW + j] = f1[base + j];
        s0[PADW + j] = f0[base + j];
    }
    __syncthreads();

    double local = 0.0;
    for (int j = tid; j < WDIM; j += 256) {
        float best1 = s1[PADW + j];
        float best0 = s0[PADW + j];
        for (int r = 1; r < WDIM; ++r) {
            float rr = (float)(r * r);
            if (rr >= best1 && rr >= best0) break;
            best1 = fminf(best1, fminf(rr + s1[PADW + j - r], rr + s1[PADW + j + r]));
            best0 = fminf(best0, fminf(rr + s0[PADW + j - r], rr + s0[PADW + j + r]));
        }
        float dist = sqrtf(best1) - sqrtf(best0);
        float x = outp[base + j];
        float prob = 1.0f / (1.0f + expf(-x));
        local += (double)(prob * dist);
    }

    // block reduction (4 waves of 64)
    double v = local;
    #pragma unroll
    for (int off = 32; off > 0; off >>= 1) v += __shfl_down(v, off, 64);
    int wid = tid >> 6, lane = tid & 63;
    if (lane == 0) swave[wid] = v;
    __syncthreads();
    if (tid == 0) {
        double s = swave[0] + swave[1] + swave[2] + swave[3];
        atomicAdd(acc, s);
    }
}

// ---------------- finalize: mean -> d_out ----------------
__global__ void finalize_kernel(const double* acc, float* out, double invN) {
    out[0] = (float)(acc[0] * invN);
}

extern "C" void kernel_launch(void* const* d_in, const int* in_sizes, int n_in,
                              void* d_out, int out_size, void* d_ws, size_t ws_size,
                              hipStream_t stream) {
    const float* outp = (const float*)d_in[0];
    const int* tgt = (const int*)d_in[1];
    int N = in_sizes[0];               // B*C*H*W = 4194304
    int B = N / (HDIM * WDIM);         // 16

    double* acc = (double*)d_ws;
    float* f1 = (float*)((char*)d_ws + 256);
    float* f0 = f1 + (size_t)N;

    zero_acc_kernel<<<1, 1, 0, stream>>>(acc);

    int cols = B * WDIM;
    vert_pass_kernel<<<(cols + 255) / 256, 256, 0, stream>>>(tgt, f1, f0, B);

    horiz_pass_kernel<<<B * HDIM, 256, 0, stream>>>(f1, f0, outp, acc);

    finalize_kernel<<<1, 1, 0, stream>>>(acc, (float*)d_out, 1.0 / (double)N);
}

// Round 2
// 47.102 us; speedup vs baseline: 4.2996x; 4.2996x over previous
//
#include <hip/hip_runtime.h>
#include <math.h>

#define HDIM 512
#define WDIM 512
#define SEG 8        // segments per column
#define SROWS 64     // rows per segment (SEG * SROWS == HDIM)
#define VCOLS 32     // columns per block in vert pass
#define ROWS_PB 4    // rows per block in horiz pass

// ---------------- pass 1: vertical squared EDT via segmented bitmask scan ----------------
// One thread per (b, w, segment-of-64-rows). Builds a 64-bit reset mask
// (bit h = tgt==1 -> reset for f1; complement -> reset for f0), exchanges
// per-segment summaries (first/last reset) through LDS to get exact scan
// carries, then computes fwd/bwd distances per row from the bitmask with
// clz/ctz. Values are exact small integers -> bit-identical to reference.
__global__ __launch_bounds__(256) void vert_pass2(const int* __restrict__ tgt,
                                                  float* __restrict__ f1,
                                                  float* __restrict__ f0) {
    __shared__ int s_fs1[SEG][VCOLS], s_ls1[SEG][VCOLS];
    __shared__ int s_fs0[SEG][VCOLS], s_ls0[SEG][VCOLS];
    __shared__ float s_c1f[SEG][VCOLS], s_c1b[SEG][VCOLS];
    __shared__ float s_c0f[SEG][VCOLS], s_c0b[SEG][VCOLS];

    int tid = threadIdx.x;
    int w = tid & (VCOLS - 1);
    int seg = tid >> 5;                     // 0..7
    int bW = WDIM / VCOLS;                  // 16
    int b = blockIdx.x / bW;
    int wbase = (blockIdx.x % bW) * VCOLS;
    size_t colbase = (size_t)b * HDIM * WDIM + wbase + w;
    const int* col = tgt + colbase + (size_t)(seg * SROWS) * WDIM;

    // build reset bitmask for f1 (reset where tgt==1)
    unsigned long long R1 = 0ull;
    #pragma unroll 8
    for (int h = 0; h < SROWS; ++h) {
        int tv = col[(size_t)h * WDIM];
        R1 |= ((unsigned long long)(tv != 0)) << h;
    }
    unsigned long long R0 = ~R1;            // reset where tgt==0

    s_fs1[seg][w] = R1 ? __builtin_ctzll(R1) : 64;
    s_ls1[seg][w] = R1 ? 63 - __builtin_clzll(R1) : -1;
    s_fs0[seg][w] = R0 ? __builtin_ctzll(R0) : 64;
    s_ls0[seg][w] = R0 ? 63 - __builtin_clzll(R0) : -1;
    __syncthreads();

    // carry chains: 128 chains (2 masks x 2 dirs x 32 cols), 8 serial steps each
    if (tid < 128) {
        int cw = tid & (VCOLS - 1);
        int md = tid >> 5;                  // 0:m1 fwd, 1:m1 bwd, 2:m0 fwd, 3:m0 bwd
        float c = 1.0e6f;                   // INF sentinel (matches reference init)
        if (md == 0) {
            for (int s = 0; s < SEG; ++s) {
                s_c1f[s][cw] = c;
                int ls = s_ls1[s][cw];
                c = (ls >= 0) ? (float)(63 - ls) : c + 64.0f;
            }
        } else if (md == 1) {
            for (int s = SEG - 1; s >= 0; --s) {
                s_c1b[s][cw] = c;
                int fs = s_fs1[s][cw];
                c = (fs < 64) ? (float)fs : c + 64.0f;
            }
        } else if (md == 2) {
            for (int s = 0; s < SEG; ++s) {
                s_c0f[s][cw] = c;
                int ls = s_ls0[s][cw];
                c = (ls >= 0) ? (float)(63 - ls) : c + 64.0f;
            }
        } else {
            for (int s = SEG - 1; s >= 0; --s) {
                s_c0b[s][cw] = c;
                int fs = s_fs0[s][cw];
                c = (fs < 64) ? (float)fs : c + 64.0f;
            }
        }
    }
    __syncthreads();

    float c1f = s_c1f[seg][w], c1b = s_c1b[seg][w];
    float c0f = s_c0f[seg][w], c0b = s_c0b[seg][w];

    float* o1 = f1 + colbase + (size_t)(seg * SROWS) * WDIM;
    float* o0 = f0 + colbase + (size_t)(seg * SROWS) * WDIM;

    unsigned long long mle = 0ull;          // bits 0..h
    for (int h = 0; h < SROWS; ++h) {
        mle = (mle << 1) | 1ull;
        // f1 (resets in R1)
        unsigned long long a = R1 & mle;
        float d1f = a ? (float)(h - (63 - __builtin_clzll(a))) : c1f + (float)(h + 1);
        unsigned long long g = R1 >> h;
        float d1b = g ? (float)__builtin_ctzll(g) : c1b + (float)(SROWS - h);
        float g1 = fminf(fminf(d1f, d1b), 1.0e6f);
        o1[(size_t)h * WDIM] = g1 * g1;
        // f0 (resets in R0)
        unsigned long long a0 = R0 & mle;
        float d0f = a0 ? (float)(h - (63 - __builtin_clzll(a0))) : c0f + (float)(h + 1);
        unsigned long long g0m = R0 >> h;
        float d0b = g0m ? (float)__builtin_ctzll(g0m) : c0b + (float)(SROWS - h);
        float g0 = fminf(fminf(d0f, d0b), 1.0e6f);
        o0[(size_t)h * WDIM] = g0 * g0;
    }
}

// ---------------- pass 2: horizontal parabola min + fused partial reduction ----------------
// One block per 4 rows. D[j] = min_k (j-k)^2 + f[k]; expand r outward, early-exit
// when r^2 >= best (exact: f >= 0). Index clamp at row ends is conservative:
// a clamped candidate r^2+f[0] with r>j is >= the true candidate j^2+f[0]
// already evaluated, so it never lowers the min incorrectly.
__global__ __launch_bounds__(256) void horiz_pass2(const float* __restrict__ f1,
                                                   const float* __restrict__ f0,
                                                   const float* __restrict__ outp,
                                                   double* __restrict__ partial) {
    __shared__ float s1[ROWS_PB][WDIM];
    __shared__ float s0[ROWS_PB][WDIM];
    __shared__ double swave[4];

    int tid = threadIdx.x;
    size_t base = (size_t)blockIdx.x * ROWS_PB * WDIM;

    for (int i = tid; i < ROWS_PB * WDIM; i += 256) {
        ((float*)s1)[i] = f1[base + i];
        ((float*)s0)[i] = f0[base + i];
    }
    __syncthreads();

    double local = 0.0;
    for (int idx = tid; idx < ROWS_PB * WDIM; idx += 256) {
        int r = idx >> 9;                   // row within block
        int j = idx & (WDIM - 1);
        const float* row1 = s1[r];
        const float* row0 = s0[r];
        float best1 = row1[j];
        float best0 = row0[j];
        for (int rad = 1; rad < WDIM; ++rad) {
            float rr = (float)(rad * rad);
            if (rr >= best1 && rr >= best0) break;
            int kl = j - rad; kl = kl < 0 ? 0 : kl;
            int kr = j + rad; kr = kr > WDIM - 1 ? WDIM - 1 : kr;
            best1 = fminf(best1, fminf(rr + row1[kl], rr + row1[kr]));
            best0 = fminf(best0, fminf(rr + row0[kl], rr + row0[kr]));
        }
        float dist = sqrtf(best1) - sqrtf(best0);
        float x = outp[base + idx];
        float prob = 1.0f / (1.0f + expf(-x));
        local += (double)(prob * dist);
    }

    // block reduction (4 waves of 64)
    double v = local;
    #pragma unroll
    for (int off = 32; off > 0; off >>= 1) v += __shfl_down(v, off, 64);
    int wid = tid >> 6, lane = tid & 63;
    if (lane == 0) swave[wid] = v;
    __syncthreads();
    if (tid == 0) partial[blockIdx.x] = swave[0] + swave[1] + swave[2] + swave[3];
}

// ---------------- finalize: sum partials -> mean -> d_out ----------------
__global__ __launch_bounds__(256) void finalize2(const double* __restrict__ partial,
                                                 float* __restrict__ out,
                                                 int npart, double invN) {
    __shared__ double swave[4];
    int tid = threadIdx.x;
    double local = 0.0;
    for (int i = tid; i < npart; i += 256) local += partial[i];
    #pragma unroll
    for (int off = 32; off > 0; off >>= 1) local += __shfl_down(local, off, 64);
    int wid = tid >> 6, lane = tid & 63;
    if (lane == 0) swave[wid] = local;
    __syncthreads();
    if (tid == 0) out[0] = (float)((swave[0] + swave[1] + swave[2] + swave[3]) * invN);
}

extern "C" void kernel_launch(void* const* d_in, const int* in_sizes, int n_in,
                              void* d_out, int out_size, void* d_ws, size_t ws_size,
                              hipStream_t stream) {
    const float* outp = (const float*)d_in[0];
    const int* tgt = (const int*)d_in[1];
    int N = in_sizes[0];                    // B*C*H*W
    int B = N / (HDIM * WDIM);              // 16

    int npart = (B * HDIM) / ROWS_PB;       // 2048

    double* partial = (double*)d_ws;
    float* f1 = (float*)((char*)d_ws + 32768);
    float* f0 = f1 + (size_t)N;

    vert_pass2<<<B * (WDIM / VCOLS), 256, 0, stream>>>(tgt, f1, f0);
    horiz_pass2<<<npart, 256, 0, stream>>>(f1, f0, outp, partial);
    finalize2<<<1, 256, 0, stream>>>(partial, (float*)d_out, npart, 1.0 / (double)N);
}

// Round 3
// 33.378 us; speedup vs baseline: 6.0675x; 1.4112x over previous
//
#include <hip/hip_runtime.h>
#include <math.h>

#define HDIM 512
#define WDIM 512
#define SEG 8        // segments per column (vert pass)
#define SROWS 64     // rows per segment
#define VCOLS 32     // columns per block (vert pass)
#define ROWS_PB 4    // rows per block (horiz pass)
#define INF_I (1 << 20)   // internal int INF; any dist >= 1023 means "1e6"
#define ENC_SENT 1023

// ---------------- pass 1: vertical 1D EDT -> signed int16 ----------------
// One thread per (b, w, 64-row segment). Builds a 64-bit reset mask, exchanges
// per-segment summaries through LDS for exact scan carries, then computes
// fwd/bwd distances per row from the bitmask via clz/ctz (int domain).
// Emits s = (tgt==1) ? -enc(g0) : +enc(g1); the pixel's own-class distance is
// always 0, so one signed value encodes both squared fields losslessly
// (real distances <= 511; enc>=1023 is the 1e6 sentinel).
__global__ __launch_bounds__(256) void vert_pass3(const int* __restrict__ tgt,
                                                  short* __restrict__ sdist) {
    __shared__ int s_fs1[SEG][VCOLS], s_ls1[SEG][VCOLS];
    __shared__ int s_fs0[SEG][VCOLS], s_ls0[SEG][VCOLS];
    __shared__ int s_c1f[SEG][VCOLS], s_c1b[SEG][VCOLS];
    __shared__ int s_c0f[SEG][VCOLS], s_c0b[SEG][VCOLS];

    int tid = threadIdx.x;
    int w = tid & (VCOLS - 1);
    int seg = tid >> 5;                     // 0..7
    int bW = WDIM / VCOLS;                  // 16
    int b = blockIdx.x / bW;
    int wbase = (blockIdx.x % bW) * VCOLS;
    size_t colbase = (size_t)b * HDIM * WDIM + wbase + w;
    const int* col = tgt + colbase + (size_t)(seg * SROWS) * WDIM;

    // reset bitmask for f1: bit h set where tgt==1
    unsigned long long R1 = 0ull;
    #pragma unroll 8
    for (int h = 0; h < SROWS; ++h) {
        int tv = col[(size_t)h * WDIM];
        R1 |= ((unsigned long long)(tv != 0)) << h;
    }
    unsigned long long R0 = ~R1;            // resets for f0: tgt==0

    s_fs1[seg][w] = R1 ? __builtin_ctzll(R1) : 64;
    s_ls1[seg][w] = R1 ? 63 - __builtin_clzll(R1) : -1;
    s_fs0[seg][w] = R0 ? __builtin_ctzll(R0) : 64;
    s_ls0[seg][w] = R0 ? 63 - __builtin_clzll(R0) : -1;
    __syncthreads();

    // carry chains: 128 chains (2 masks x 2 dirs x 32 cols), 8 serial steps
    if (tid < 128) {
        int cw = tid & (VCOLS - 1);
        int md = tid >> 5;
        int c = INF_I;
        if (md == 0) {
            for (int s = 0; s < SEG; ++s) {
                s_c1f[s][cw] = c;
                int ls = s_ls1[s][cw];
                c = (ls >= 0) ? (63 - ls) : c + 64;
            }
        } else if (md == 1) {
            for (int s = SEG - 1; s >= 0; --s) {
                s_c1b[s][cw] = c;
                int fs = s_fs1[s][cw];
                c = (fs < 64) ? fs : c + 64;
            }
        } else if (md == 2) {
            for (int s = 0; s < SEG; ++s) {
                s_c0f[s][cw] = c;
                int ls = s_ls0[s][cw];
                c = (ls >= 0) ? (63 - ls) : c + 64;
            }
        } else {
            for (int s = SEG - 1; s >= 0; --s) {
                s_c0b[s][cw] = c;
                int fs = s_fs0[s][cw];
                c = (fs < 64) ? fs : c + 64;
            }
        }
    }
    __syncthreads();

    int c1f = s_c1f[seg][w], c1b = s_c1b[seg][w];
    int c0f = s_c0f[seg][w], c0b = s_c0b[seg][w];

    short* os = sdist + colbase + (size_t)(seg * SROWS) * WDIM;

    unsigned long long mle = 0ull;          // bits 0..h
    for (int h = 0; h < SROWS; ++h) {
        mle = (mle << 1) | 1ull;
        // g1: dist to nearest tgt==1 in column
        unsigned long long a1 = R1 & mle;
        int d1f = a1 ? (h - (63 - __builtin_clzll(a1))) : c1f + h + 1;
        unsigned long long b1 = R1 >> h;
        int d1b = b1 ? __builtin_ctzll(b1) : c1b + (SROWS - h);
        int g1 = min(d1f, d1b);
        // g0: dist to nearest tgt==0 in column
        unsigned long long a0 = R0 & mle;
        int d0f = a0 ? (h - (63 - __builtin_clzll(a0))) : c0f + h + 1;
        unsigned long long b0 = R0 >> h;
        int d0b = b0 ? __builtin_ctzll(b0) : c0b + (SROWS - h);
        int g0 = min(d0f, d0b);

        int e1 = min(g1, ENC_SENT);
        int e0 = min(g0, ENC_SENT);
        short sval = ((R1 >> h) & 1ull) ? (short)(-e0) : (short)e1;
        os[(size_t)h * WDIM] = sval;
    }
}

// ---------------- pass 2: horizontal parabola min + fused partial reduce ----------------
// One block per 4 rows. Each pixel scans ONLY its opposite-class envelope:
// dist = +sqrt(D1) at tgt==0 pixels, -sqrt(D0) at tgt==1 pixels (the own-class
// 2D distance is exactly 0). Early-exit when r^2 >= best is exact (f >= 0);
// index clamp at row ends is conservative (clamped candidate >= an already
// evaluated true candidate).
__global__ __launch_bounds__(256) void horiz_pass3(const short* __restrict__ sdist,
                                                   const float* __restrict__ outp,
                                                   double* __restrict__ partial) {
    __shared__ float sf1[ROWS_PB * WDIM];
    __shared__ float sf0[ROWS_PB * WDIM];
    __shared__ double swave[4];

    int tid = threadIdx.x;
    size_t base = (size_t)blockIdx.x * ROWS_PB * WDIM;

    for (int i = tid; i < ROWS_PB * WDIM; i += 256) {
        int sv = sdist[base + i];           // sign-extended
        int neg = sv < 0;
        int e = neg ? -sv : sv;
        float g = (e >= ENC_SENT) ? 1.0e6f : (float)e;
        float f = g * g;
        sf1[i] = neg ? 0.0f : f;
        sf0[i] = neg ? f : 0.0f;
    }
    __syncthreads();

    double local = 0.0;
    for (int idx = tid; idx < ROWS_PB * WDIM; idx += 256) {
        int row = idx >> 9;
        int j = idx & (WDIM - 1);
        const float* env1 = sf1 + row * WDIM;
        const float* env0 = sf0 + row * WDIM;
        int cls0 = env1[j] > 0.0f;          // f1[j] > 0 <=> tgt==0
        const float* env = cls0 ? env1 : env0;
        float best = env[j];
        for (int rad = 1; rad < WDIM; ++rad) {
            float rr = (float)(rad * rad);
            if (rr >= best) break;
            int kl = j - rad; kl = kl < 0 ? 0 : kl;
            int kr = j + rad; kr = kr > WDIM - 1 ? WDIM - 1 : kr;
            best = fminf(best, fminf(rr + env[kl], rr + env[kr]));
        }
        float sd = sqrtf(best);
        float dist = cls0 ? sd : -sd;
        float x = outp[base + idx];
        float prob = 1.0f / (1.0f + expf(-x));
        local += (double)(prob * dist);
    }

    // block reduction (4 waves of 64)
    double v = local;
    #pragma unroll
    for (int off = 32; off > 0; off >>= 1) v += __shfl_down(v, off, 64);
    int wid = tid >> 6, lane = tid & 63;
    if (lane == 0) swave[wid] = v;
    __syncthreads();
    if (tid == 0) partial[blockIdx.x] = swave[0] + swave[1] + swave[2] + swave[3];
}

// ---------------- finalize: sum partials -> mean ----------------
__global__ __launch_bounds__(256) void finalize3(const double* __restrict__ partial,
                                                 float* __restrict__ out,
                                                 int npart, double invN) {
    __shared__ double swave[4];
    int tid = threadIdx.x;
    double local = 0.0;
    for (int i = tid; i < npart; i += 256) local += partial[i];
    #pragma unroll
    for (int off = 32; off > 0; off >>= 1) local += __shfl_down(local, off, 64);
    int wid = tid >> 6, lane = tid & 63;
    if (lane == 0) swave[wid] = local;
    __syncthreads();
    if (tid == 0) out[0] = (float)((swave[0] + swave[1] + swave[2] + swave[3]) * invN);
}

extern "C" void kernel_launch(void* const* d_in, const int* in_sizes, int n_in,
                              void* d_out, int out_size, void* d_ws, size_t ws_size,
                              hipStream_t stream) {
    const float* outp = (const float*)d_in[0];
    const int* tgt = (const int*)d_in[1];
    int N = in_sizes[0];                    // B*C*H*W
    int B = N / (HDIM * WDIM);              // 16

    int npart = (B * HDIM) / ROWS_PB;       // 2048

    double* partial = (double*)d_ws;
    short* sdist = (short*)((char*)d_ws + 32768);

    vert_pass3<<<B * (WDIM / VCOLS), 256, 0, stream>>>(tgt, sdist);
    horiz_pass3<<<npart, 256, 0, stream>>>(sdist, outp, partial);
    finalize3<<<1, 256, 0, stream>>>(partial, (float*)d_out, npart, 1.0 / (double)N);
}